// Round 4
// baseline (968.696 us; speedup 1.0000x reference)
//
#include <hip/hip_runtime.h>
#include <stdint.h>

#define HIDDEN 4096
#define M_TOK 8192   // B*S
#define KDIM 4096

typedef __attribute__((ext_vector_type(8))) __bf16 bf16x8;
typedef __attribute__((ext_vector_type(4))) float f32x4;
typedef __attribute__((ext_vector_type(16))) float f32x16;
typedef __attribute__((ext_vector_type(8))) unsigned short u16x8;

#define GAS __attribute__((address_space(1)))
#define LAS __attribute__((address_space(3)))

__device__ __forceinline__ unsigned short f2bf(float f) {
  unsigned int u = __float_as_uint(f);
  u += 0x7FFFu + ((u >> 16) & 1u);
  return (unsigned short)(u >> 16);
}
__device__ __forceinline__ float bf2f(unsigned short b) {
  return __uint_as_float(((unsigned int)b) << 16);
}

// ---------- fp32 -> bf16, 8 elems/thread ----------
__global__ __launch_bounds__(256) void cvt_kernel(const float* __restrict__ in,
                                                  unsigned short* __restrict__ out,
                                                  int n8) {
  int i = blockIdx.x * 256 + threadIdx.x;
  if (i >= n8) return;
  const f32x4* p = (const f32x4*)in + (size_t)2 * i;
  f32x4 a = p[0], b = p[1];
  u16x8 o;
  o[0] = f2bf(a.x); o[1] = f2bf(a.y); o[2] = f2bf(a.z); o[3] = f2bf(a.w);
  o[4] = f2bf(b.x); o[5] = f2bf(b.y); o[6] = f2bf(b.z); o[7] = f2bf(b.w);
  ((u16x8*)out)[i] = o;
}

// ============================================================================
// 256x256 QKV GEMM, 32x32x16 MFMA, 4 phases per K-tile (BK=64).
// 512 thr = 8 waves (2M x 4N); per-wave out 128x64 = 4x2 frags of 32x32.
// LDS 128 KiB: A[2 buf][2 half(128 rows)][row][64K] + B likewise.
// Swizzle: chunk ^= (row&7) (16B chunks), via pre-swizzled global source
// (linear gload_lds dest) + same XOR on ds_read addr. Read ladder 12/8/4/0:
// P1 = all 8 B frags + A ks0; P2 = A ks1,ks2; P3 = A ks3; P4 = none.
// Stages: P1=A1(next buf), P2=B0, P3=B1, P4=A0 (this buf, tile+2); WAR-safe
// since B fully read at P1-MID, A half read by P3-MID. vmcnt(6) at P4 only.
// ============================================================================
#define BAR() __builtin_amdgcn_s_barrier()
#define PRIO(p) __builtin_amdgcn_s_setprio(p)
#define VMC6() asm volatile("s_waitcnt vmcnt(6)" ::: "memory")
#define VMC4() asm volatile("s_waitcnt vmcnt(4)" ::: "memory")
#define VMC0() asm volatile("s_waitcnt vmcnt(0)" ::: "memory")
#define PH_MID() do { __builtin_amdgcn_s_barrier(); \
  asm volatile("s_waitcnt lgkmcnt(0)" ::: "memory"); \
  __builtin_amdgcn_sched_barrier(0); } while (0)

__global__ __launch_bounds__(512, 2) void gemm_qkv(
    const unsigned short* __restrict__ A,   // [8192][4096] bf16
    const unsigned short* __restrict__ W,   // [12288][4096] bf16 (wq;wk;wv)
    const float* __restrict__ bias,         // [12288]
    unsigned short* __restrict__ out) {     // [3][8192][4096] bf16
  __shared__ __attribute__((aligned(16))) unsigned short lds[65536];  // 128 KiB

  int tid = threadIdx.x;
  int lane = tid & 63;
  int w = tid >> 6;
  int wm = w >> 2;        // 0..1 -> rows wm*128
  int wn = w & 3;         // 0..3 -> cols wn*64
  int l31 = lane & 31;
  int lg = lane >> 5;     // k-group
  int l7 = lane & 7;

  // tile mapping with XCD swizzle (1536 blocks % 8 == 0)
  int bid = blockIdx.x;
  int wg = (bid & 7) * 192 + (bid >> 3);
  int tm = wg / 48;
  int tn = wg - tm * 48;
  int m0 = tm << 8, n0 = tn << 8;

  // ---- staging source: pre-swizzled global col (3-bit XOR by row&7) ----
  int rp = tid >> 3;                                     // 0..63 row within chunk
  int ce = ((tid & 7) << 3) ^ ((rp & 7) << 3);           // col elems, swizzled
  const unsigned short* aSrc = A + (size_t)(m0 + rp) * KDIM + ce;
  const unsigned short* bSrc = W + (size_t)(n0 + rp) * KDIM + ce;
  int tid8 = tid * 8;  // linear LDS shorts offset for this thread's 16B

#define STA(b, h, kt) do { \
  __builtin_amdgcn_global_load_lds((GAS void*)(aSrc + (size_t)((h)*128) * KDIM + (kt)*64), \
      (LAS void*)(lds + (b)*16384 + (h)*8192 + tid8), 16, 0, 0); \
  __builtin_amdgcn_global_load_lds((GAS void*)(aSrc + (size_t)((h)*128 + 64) * KDIM + (kt)*64), \
      (LAS void*)(lds + (b)*16384 + (h)*8192 + 4096 + tid8), 16, 0, 0); } while (0)
#define STB(b, h, kt) do { \
  __builtin_amdgcn_global_load_lds((GAS void*)(bSrc + (size_t)((h)*128) * KDIM + (kt)*64), \
      (LAS void*)(lds + 32768 + (b)*16384 + (h)*8192 + tid8), 16, 0, 0); \
  __builtin_amdgcn_global_load_lds((GAS void*)(bSrc + (size_t)((h)*128 + 64) * KDIM + (kt)*64), \
      (LAS void*)(lds + 32768 + (b)*16384 + (h)*8192 + 4096 + tid8), 16, 0, 0); } while (0)

  // ---- fragment read addressing (32x32x16):
  // A frag (mi,ks): row = wm*128 + mi*32 + l31 -> half wm, lr = mi*32+l31;
  //   k-chunk = 2ks + lg, stored at chunk ^ (lr&7) = (lg ^ l7) ^ 2ks.
  int aRd0 = wm * 8192 + l31 * 64 + ((lg ^ l7) << 3);
  int aK0 = aRd0, aK1 = aRd0 ^ 16, aK2 = aRd0 ^ 32, aK3 = aRd0 ^ 48;
  // B frag (nj,ks): row = wn*64 + nj*32 + l31 -> half wn>>1, lr=(wn&1)*64+nj*32+l31
  int bRd0 = (wn >> 1) * 8192 + (wn & 1) * 4096 + l31 * 64 + ((lg ^ l7) << 3);
  int bK0 = bRd0, bK1 = bRd0 ^ 16, bK2 = bRd0 ^ 32, bK3 = bRd0 ^ 48;

#define RA(c, mi, ks) avv[ks][mi] = *(const bf16x8*)(lds + (c)*16384 + aK##ks + (mi)*2048)
#define RB(c, nj, ks) bvv[nj][ks] = *(const bf16x8*)(lds + 32768 + (c)*16384 + bK##ks + (nj)*2048)

  bf16x8 avv[4][4];
  bf16x8 bvv[2][4];
  f32x16 acc[4][2] = {};

#define MF(mi, nj, ks) acc[mi][nj] = __builtin_amdgcn_mfma_f32_32x32x16_bf16( \
    avv[ks][mi], bvv[nj][ks], acc[mi][nj], 0, 0, 0)
#define MMKS(ks) do { MF(0,0,ks); MF(0,1,ks); MF(1,0,ks); MF(1,1,ks); \
                      MF(2,0,ks); MF(2,1,ks); MF(3,0,ks); MF(3,1,ks); } while (0)

#define RP1(c) do { RB(c,0,0); RB(c,0,1); RB(c,0,2); RB(c,0,3); \
                    RB(c,1,0); RB(c,1,1); RB(c,1,2); RB(c,1,3); \
                    RA(c,0,0); RA(c,1,0); RA(c,2,0); RA(c,3,0); } while (0)
#define RP2(c) do { RA(c,0,1); RA(c,1,1); RA(c,2,1); RA(c,3,1); \
                    RA(c,0,2); RA(c,1,2); RA(c,2,2); RA(c,3,2); } while (0)
#define RP3(c) do { RA(c,0,3); RA(c,1,3); RA(c,2,3); RA(c,3,3); } while (0)

  // ---- prologue: kt0 full (B0,B1,A0,A1) + kt1 (B0,B1,A0); 6 loads in flight ----
  STB(0, 0, 0); STB(0, 1, 0); STA(0, 0, 0); STA(0, 1, 0);
  VMC4();
  STB(1, 0, 1); STB(1, 1, 1); STA(1, 0, 1);
  VMC6();
  BAR();

  // ---- main loop: 31 iters x 2 K-tiles ----
  for (int it = 0; it < 31; ++it) {
    int k1 = 2 * it + 1, k2 = 2 * it + 2, k3 = 2 * it + 3;
    // K-tile 2it from buf0
    RP1(0); STA(1, 1, k1); PH_MID(); PRIO(1); MMKS(0); PRIO(0); BAR();
    RP2(0); STB(0, 0, k2); PH_MID(); PRIO(1); MMKS(1); PRIO(0); BAR();
    RP3(0); STB(0, 1, k2); PH_MID(); PRIO(1); MMKS(2); PRIO(0); BAR();
            STA(0, 0, k2); PH_MID(); PRIO(1); MMKS(3); PRIO(0); VMC6(); BAR();
    // K-tile 2it+1 from buf1
    RP1(1); STA(0, 1, k2); PH_MID(); PRIO(1); MMKS(0); PRIO(0); BAR();
    RP2(1); STB(1, 0, k3); PH_MID(); PRIO(1); MMKS(1); PRIO(0); BAR();
    RP3(1); STB(1, 1, k3); PH_MID(); PRIO(1); MMKS(2); PRIO(0); BAR();
            STA(1, 0, k3); PH_MID(); PRIO(1); MMKS(3); PRIO(0); VMC6(); BAR();
  }
  // epilogue: kt62 (buf0) + kt63 (buf1)
  RP1(0); STA(1, 1, 63); PH_MID(); PRIO(1); MMKS(0); PRIO(0); BAR();
  RP2(0);                PH_MID(); PRIO(1); MMKS(1); PRIO(0); BAR();
  RP3(0);                PH_MID(); PRIO(1); MMKS(2); PRIO(0); BAR();
                         PH_MID(); PRIO(1); MMKS(3); PRIO(0); VMC0(); BAR();
  RP1(1);                PH_MID(); PRIO(1); MMKS(0); PRIO(0); BAR();
  RP2(1);                PH_MID(); PRIO(1); MMKS(1); PRIO(0); BAR();
  RP3(1);                PH_MID(); PRIO(1); MMKS(2); PRIO(0); BAR();
                         PH_MID(); PRIO(1); MMKS(3); PRIO(0);

  // ---- C write (32x32 layout): col = l31 (+32*nj), row = (r&3)+8*(r>>2)+4*lg (+32*mi) ----
  int matc = n0 >> 12;
  int ncol = (n0 & 4095) + wn * 64;
  unsigned short* O = out + (size_t)matc * M_TOK * HIDDEN;
  float bb0 = bias[n0 + wn * 64 + l31];
  float bb1 = bias[n0 + wn * 64 + 32 + l31];
#pragma unroll
  for (int mi = 0; mi < 4; ++mi) {
#pragma unroll
    for (int r = 0; r < 16; ++r) {
      int row = m0 + wm * 128 + mi * 32 + (r & 3) + 8 * (r >> 2) + 4 * lg;
      size_t rb = (size_t)row * HIDDEN + ncol + l31;
      O[rb] = f2bf(acc[mi][0][r] + bb0);
      O[rb + 32] = f2bf(acc[mi][1][r] + bb1);
    }
  }
}

// ---------- per-token 32x32 head attention ----------
__global__ __launch_bounds__(256) void attn_kernel(const unsigned short* __restrict__ qkv,
                                                   float* __restrict__ out) {
  __shared__ float sQ[32 * 132];
  __shared__ float sK[32 * 132];
  __shared__ float sV[32 * 132];
  __shared__ float sP[32 * 33];

  int m = blockIdx.x;
  int tid = threadIdx.x;
  const unsigned short* gq = qkv + (size_t)m * HIDDEN;
  const unsigned short* gk = gq + (size_t)M_TOK * HIDDEN;
  const unsigned short* gv = gk + (size_t)M_TOK * HIDDEN;

  int row = tid >> 3;
  int cb = (tid & 7) << 4;
  int go = row * 128 + cb;
  int lo = row * 132 + cb;
  {
    u16x8 x0 = *(const u16x8*)(gq + go);
    u16x8 x1 = *(const u16x8*)(gq + go + 8);
#pragma unroll
    for (int j = 0; j < 8; ++j) { sQ[lo + j] = bf2f(x0[j]); sQ[lo + 8 + j] = bf2f(x1[j]); }
    x0 = *(const u16x8*)(gk + go);
    x1 = *(const u16x8*)(gk + go + 8);
#pragma unroll
    for (int j = 0; j < 8; ++j) { sK[lo + j] = bf2f(x0[j]); sK[lo + 8 + j] = bf2f(x1[j]); }
    x0 = *(const u16x8*)(gv + go);
    x1 = *(const u16x8*)(gv + go + 8);
#pragma unroll
    for (int j = 0; j < 8; ++j) { sV[lo + j] = bf2f(x0[j]); sV[lo + 8 + j] = bf2f(x1[j]); }
  }
  __syncthreads();

  int h = tid >> 3;
  int t4 = (tid & 7) << 2;
  const f32x4* qr = (const f32x4*)(sQ + h * 132);
  const f32x4* k0 = (const f32x4*)(sK + (t4 + 0) * 132);
  const f32x4* k1 = (const f32x4*)(sK + (t4 + 1) * 132);
  const f32x4* k2 = (const f32x4*)(sK + (t4 + 2) * 132);
  const f32x4* k3 = (const f32x4*)(sK + (t4 + 3) * 132);
  float s0 = 0.f, s1 = 0.f, s2 = 0.f, s3 = 0.f;
#pragma unroll
  for (int d = 0; d < 32; ++d) {
    f32x4 q = qr[d];
    f32x4 a = k0[d]; s0 += q.x * a.x + q.y * a.y + q.z * a.z + q.w * a.w;
    f32x4 b = k1[d]; s1 += q.x * b.x + q.y * b.y + q.z * b.z + q.w * b.w;
    f32x4 c = k2[d]; s2 += q.x * c.x + q.y * c.y + q.z * c.z + q.w * c.w;
    f32x4 e = k3[d]; s3 += q.x * e.x + q.y * e.y + q.z * e.z + q.w * e.w;
  }
  const float scale = 0.08838834764831845f;  // 1/sqrt(128)
  s0 *= scale; s1 *= scale; s2 *= scale; s3 *= scale;
  float mx = fmaxf(fmaxf(s0, s1), fmaxf(s2, s3));
  mx = fmaxf(mx, __shfl_xor(mx, 1));
  mx = fmaxf(mx, __shfl_xor(mx, 2));
  mx = fmaxf(mx, __shfl_xor(mx, 4));
  float e0 = __expf(s0 - mx), e1 = __expf(s1 - mx), e2 = __expf(s2 - mx), e3 = __expf(s3 - mx);
  float sum = e0 + e1 + e2 + e3;
  sum += __shfl_xor(sum, 1);
  sum += __shfl_xor(sum, 2);
  sum += __shfl_xor(sum, 4);
  float inv = 1.0f / sum;
  sP[h * 33 + t4 + 0] = e0 * inv;
  sP[h * 33 + t4 + 1] = e1 * inv;
  sP[h * 33 + t4 + 2] = e2 * inv;
  sP[h * 33 + t4 + 3] = e3 * inv;
  __syncthreads();

  int d0 = (tid & 7) << 4;
  f32x4 o0 = {0.f, 0.f, 0.f, 0.f}, o1 = o0, o2 = o0, o3 = o0;
  const float* pr = sP + h * 33;
#pragma unroll
  for (int t = 0; t < 32; ++t) {
    float p = pr[t];
    const f32x4* vr = (const f32x4*)(sV + t * 132 + d0);
    o0 += p * vr[0];
    o1 += p * vr[1];
    o2 += p * vr[2];
    o3 += p * vr[3];
  }
  f32x4* op = (f32x4*)(out + (size_t)m * HIDDEN + h * 128 + d0);
  op[0] = o0; op[1] = o1; op[2] = o2; op[3] = o3;
}

extern "C" void kernel_launch(void* const* d_in, const int* in_sizes, int n_in,
                              void* d_out, int out_size, void* d_ws, size_t ws_size,
                              hipStream_t stream) {
  const float* hs = (const float*)d_in[0];
  const float* wq = (const float*)d_in[1];
  const float* bq = (const float*)d_in[2];
  const float* wk = (const float*)d_in[3];
  const float* bk = (const float*)d_in[4];
  const float* wv = (const float*)d_in[5];
  const float* bv = (const float*)d_in[6];
  // wl/bl latent projection: unused by output — skipped.

  char* ws = (char*)d_ws;
  const size_t HS_OFF = 0;                    // 64 MiB
  const size_t W_OFF = 67108864;              // 96 MiB
  const size_t QKV_OFF = 167772160;           // 192 MiB
  const size_t BIAS_OFF = 369098752;          // 48 KiB
  const size_t NEED = 369147904;
  if (ws_size < NEED) return;

  unsigned short* hsb = (unsigned short*)(ws + HS_OFF);
  unsigned short* wb = (unsigned short*)(ws + W_OFF);
  unsigned short* qkv = (unsigned short*)(ws + QKV_OFF);
  float* bias = (float*)(ws + BIAS_OFF);

  cvt_kernel<<<16384, 256, 0, stream>>>(hs, hsb, 4194304);
  cvt_kernel<<<8192, 256, 0, stream>>>(wq, wb, 2097152);
  cvt_kernel<<<8192, 256, 0, stream>>>(wk, wb + 16777216, 2097152);
  cvt_kernel<<<8192, 256, 0, stream>>>(wv, wb + 33554432, 2097152);
  hipMemcpyAsync(bias, bq, 16384, hipMemcpyDeviceToDevice, stream);
  hipMemcpyAsync(bias + 4096, bk, 16384, hipMemcpyDeviceToDevice, stream);
  hipMemcpyAsync(bias + 8192, bv, 16384, hipMemcpyDeviceToDevice, stream);

  gemm_qkv<<<1536, 512, 0, stream>>>(hsb, wb, bias, qkv);   // 32 x 48 tiles
  attn_kernel<<<8192, 256, 0, stream>>>(qkv, (float*)d_out);
}

// Round 5
// 865.248 us; speedup vs baseline: 1.1196x; 1.1196x over previous
//
#include <hip/hip_runtime.h>
#include <stdint.h>

#define HIDDEN 4096
#define M_TOK 8192   // B*S
#define KDIM 4096

typedef __attribute__((ext_vector_type(8))) __bf16 bf16x8;
typedef __attribute__((ext_vector_type(4))) float f32x4;
typedef __attribute__((ext_vector_type(8))) unsigned short u16x8;

#define GAS __attribute__((address_space(1)))
#define LAS __attribute__((address_space(3)))

__device__ __forceinline__ unsigned short f2bf(float f) {
  unsigned int u = __float_as_uint(f);
  u += 0x7FFFu + ((u >> 16) & 1u);
  return (unsigned short)(u >> 16);
}
__device__ __forceinline__ float bf2f(unsigned short b) {
  return __uint_as_float(((unsigned int)b) << 16);
}

// ---------- fp32 -> bf16, 8 elems/thread ----------
__global__ __launch_bounds__(256) void cvt_kernel(const float* __restrict__ in,
                                                  unsigned short* __restrict__ out,
                                                  int n8) {
  int i = blockIdx.x * 256 + threadIdx.x;
  if (i >= n8) return;
  const f32x4* p = (const f32x4*)in + (size_t)2 * i;
  f32x4 a = p[0], b = p[1];
  u16x8 o;
  o[0] = f2bf(a.x); o[1] = f2bf(a.y); o[2] = f2bf(a.z); o[3] = f2bf(a.w);
  o[4] = f2bf(b.x); o[5] = f2bf(b.y); o[6] = f2bf(b.z); o[7] = f2bf(b.w);
  ((u16x8*)out)[i] = o;
}

// ============================================================================
// 256x256 8-phase QKV GEMM — R3 structure (16x16x32 MFMA, 0 bank conflicts)
// + 2D XCD slab mapping: XCD c owns tm in [4c,4c+4); co-resident 32 blocks
// form a 4x8 (tm x tn) rectangle -> per-XCD-round panel footprint 24MB
// (was 66MB with 1D swizzle), A-panels XCD-resident across tn rounds.
// NOTE (R4 post-mortem): 32x32x16 MFMA with this swizzle re-creates 7.5e7
// LDS bank conflicts (chunk-sharing lanes land on identical bank offsets);
// 16x16x32 measured 0. Keep 16x16x32.
// ============================================================================
#define BAR() __builtin_amdgcn_s_barrier()
#define PRIO(p) __builtin_amdgcn_s_setprio(p)
#define VMC6() asm volatile("s_waitcnt vmcnt(6)" ::: "memory")
#define VMC4() asm volatile("s_waitcnt vmcnt(4)" ::: "memory")
#define VMC0() asm volatile("s_waitcnt vmcnt(0)" ::: "memory")
#define PH_MID() do { __builtin_amdgcn_s_barrier(); \
  asm volatile("s_waitcnt lgkmcnt(0)" ::: "memory"); \
  __builtin_amdgcn_sched_barrier(0); } while (0)

__global__ __launch_bounds__(512, 2) void gemm_qkv(
    const unsigned short* __restrict__ A,   // [8192][4096] bf16
    const unsigned short* __restrict__ W,   // [12288][4096] bf16 (wq;wk;wv)
    const float* __restrict__ bias,         // [12288]
    unsigned short* __restrict__ out) {     // [3][8192][4096] bf16
  __shared__ __attribute__((aligned(16))) unsigned short lds[65536];  // 128 KiB

  int tid = threadIdx.x;
  int lane = tid & 63;
  int w = tid >> 6;
  int wm = w >> 2;        // 0..1 -> rows wm*128
  int wn = w & 3;         // 0..3 -> cols wn*64
  int l16 = lane & 15;
  int lk = lane >> 4;

  // ---- 2D XCD slab mapping (bijective; grid = 1536 = 8 XCD * 4 tm * 48 tn) ----
  int bid = blockIdx.x;
  int xcd = bid & 7;          // dispatch round-robins XCDs
  int local = bid >> 3;       // 0..191 within XCD
  int r = local >> 5;         // 0..5 tn-round
  int i = local & 31;         // 0..31 co-resident slot
  int tm = (xcd << 2) + (i >> 3);   // 4 tm rows per XCD
  int tn = (r << 3) + (i & 7);      // 8 tn cols per round
  int m0 = tm << 8, n0 = tn << 8;

  // ---- staging source: pre-swizzled global col (3-bit XOR by row&7) ----
  int rp = tid >> 3;                                     // 0..63 row within chunk
  int ce = ((tid & 7) << 3) ^ ((rp & 7) << 3);           // col elems, swizzled
  const unsigned short* aSrc = A + (size_t)(m0 + rp) * KDIM + ce;
  const unsigned short* bSrc = W + (size_t)(n0 + rp) * KDIM + ce;
  int tid8 = tid * 8;  // linear LDS shorts offset for this thread's 16B

#define STA(b, h, kt) do { \
  __builtin_amdgcn_global_load_lds((GAS void*)(aSrc + (size_t)((h)*128) * KDIM + (kt)*64), \
      (LAS void*)(lds + (b)*16384 + (h)*8192 + tid8), 16, 0, 0); \
  __builtin_amdgcn_global_load_lds((GAS void*)(aSrc + (size_t)((h)*128 + 64) * KDIM + (kt)*64), \
      (LAS void*)(lds + (b)*16384 + (h)*8192 + 4096 + tid8), 16, 0, 0); } while (0)
#define STB(b, h, kt) do { \
  __builtin_amdgcn_global_load_lds((GAS void*)(bSrc + (size_t)((h)*128) * KDIM + (kt)*64), \
      (LAS void*)(lds + 32768 + (b)*16384 + (h)*8192 + tid8), 16, 0, 0); \
  __builtin_amdgcn_global_load_lds((GAS void*)(bSrc + (size_t)((h)*128 + 64) * KDIM + (kt)*64), \
      (LAS void*)(lds + 32768 + (b)*16384 + (h)*8192 + 4096 + tid8), 16, 0, 0); } while (0)

  // ---- fragment read addressing: same 3-bit XOR (row&7 == l16&7 for all frags) ----
  int colbase = (lk << 3) ^ ((l16 & 7) << 3);            // shorts, ks=0
  int aRd = wm * 8192 + l16 * 64 + colbase;
  int bRd = (wn >> 1) * 8192 + (wn & 1) * 4096 + l16 * 64 + colbase;

  // ks=1 flips linear bit5 (col bit5) -- part of the XOR field
#define RD_A(c, mi, ks) (*(const bf16x8*)(lds + (c)*16384 + (((aRd) + (mi)*1024) ^ ((ks)*32))))
#define RD_B(c, nj, ks) (*(const bf16x8*)(lds + 32768 + (c)*16384 + (((bRd) + (nj)*1024) ^ ((ks)*32))))

  bf16x8 av[8][2];
  bf16x8 bv[4][2];
  f32x4 acc[8][4] = {};

#define RP1(c) do { \
  bv[0][0]=RD_B(c,0,0); bv[0][1]=RD_B(c,0,1); bv[1][0]=RD_B(c,1,0); bv[1][1]=RD_B(c,1,1); \
  bv[2][0]=RD_B(c,2,0); bv[2][1]=RD_B(c,2,1); bv[3][0]=RD_B(c,3,0); bv[3][1]=RD_B(c,3,1); \
  av[0][0]=RD_A(c,0,0); av[0][1]=RD_A(c,0,1); av[1][0]=RD_A(c,1,0); av[1][1]=RD_A(c,1,1); } while (0)
#define RP2(c) do { \
  av[2][0]=RD_A(c,2,0); av[2][1]=RD_A(c,2,1); av[3][0]=RD_A(c,3,0); av[3][1]=RD_A(c,3,1); \
  av[4][0]=RD_A(c,4,0); av[4][1]=RD_A(c,4,1); av[5][0]=RD_A(c,5,0); av[5][1]=RD_A(c,5,1); } while (0)
#define RP3(c) do { \
  av[6][0]=RD_A(c,6,0); av[6][1]=RD_A(c,6,1); av[7][0]=RD_A(c,7,0); av[7][1]=RD_A(c,7,1); } while (0)

#define MFMA2(mi, nj) do { \
  acc[mi][nj] = __builtin_amdgcn_mfma_f32_16x16x32_bf16(av[mi][0], bv[nj][0], acc[mi][nj], 0, 0, 0); \
  acc[mi][nj] = __builtin_amdgcn_mfma_f32_16x16x32_bf16(av[mi][1], bv[nj][1], acc[mi][nj], 0, 0, 0); } while (0)
#define MM(mi) do { MFMA2(mi,0); MFMA2(mi,1); MFMA2(mi,2); MFMA2(mi,3); } while (0)

  // ---- prologue: kt0 full (B0,B1,A0,A1) + kt1 (B0,B1,A0); 6 loads in flight ----
  STB(0, 0, 0); STB(0, 1, 0); STA(0, 0, 0); STA(0, 1, 0);
  VMC4();
  STB(1, 0, 1); STB(1, 1, 1); STA(1, 0, 1);
  VMC6();
  BAR();

  // ---- main loop: 31 iters x 2 K-tiles; epilogue iter drains kt62/kt63 ----
  for (int it = 0; it < 31; ++it) {
    int k1 = 2 * it + 1, k2 = 2 * it + 2, k3 = 2 * it + 3;
    // K-tile 2it from buf0
    RP1(0); STA(1, 1, k1); PH_MID(); PRIO(1); MM(0); MM(1); PRIO(0); BAR();
    RP2(0); STB(0, 0, k2); PH_MID(); PRIO(1); MM(2); MM(3); PRIO(0); BAR();
    RP3(0); STB(0, 1, k2); PH_MID(); PRIO(1); MM(4); MM(5); PRIO(0); BAR();
            STA(0, 0, k2); PH_MID(); PRIO(1); MM(6); MM(7); PRIO(0); VMC6(); BAR();
    // K-tile 2it+1 from buf1
    RP1(1); STA(0, 1, k2); PH_MID(); PRIO(1); MM(0); MM(1); PRIO(0); BAR();
    RP2(1); STB(1, 0, k3); PH_MID(); PRIO(1); MM(2); MM(3); PRIO(0); BAR();
    RP3(1); STB(1, 1, k3); PH_MID(); PRIO(1); MM(4); MM(5); PRIO(0); BAR();
            STA(1, 0, k3); PH_MID(); PRIO(1); MM(6); MM(7); PRIO(0); VMC6(); BAR();
  }
  // epilogue: kt62 (buf0) + kt63 (buf1), stage only A1 of kt63, drain vmcnt
  RP1(0); STA(1, 1, 63); PH_MID(); PRIO(1); MM(0); MM(1); PRIO(0); BAR();
  RP2(0);                PH_MID(); PRIO(1); MM(2); MM(3); PRIO(0); BAR();
  RP3(0);                PH_MID(); PRIO(1); MM(4); MM(5); PRIO(0); BAR();
                         PH_MID(); PRIO(1); MM(6); MM(7); PRIO(0); VMC0(); BAR();
  RP1(1);                PH_MID(); PRIO(1); MM(0); MM(1); PRIO(0); BAR();
  RP2(1);                PH_MID(); PRIO(1); MM(2); MM(3); PRIO(0); BAR();
  RP3(1);                PH_MID(); PRIO(1); MM(4); MM(5); PRIO(0); BAR();
                         PH_MID(); PRIO(1); MM(6); MM(7); PRIO(0);

  // ---- C write: col = l16 + 16*nj (+ wn*64), row = lk*4 + r + 16*mi (+ wm*128) ----
  int matc = n0 >> 12;
  int ncol = (n0 & 4095) + wn * 64;
  unsigned short* O = out + (size_t)matc * M_TOK * HIDDEN;
  float bb[4];
#pragma unroll
  for (int nj = 0; nj < 4; ++nj) bb[nj] = bias[n0 + wn * 64 + nj * 16 + l16];
#pragma unroll
  for (int mi = 0; mi < 8; ++mi) {
#pragma unroll
    for (int r = 0; r < 4; ++r) {
      int row = m0 + wm * 128 + mi * 16 + lk * 4 + r;
      size_t rb = (size_t)row * HIDDEN + ncol + l16;
#pragma unroll
      for (int nj = 0; nj < 4; ++nj)
        O[rb + nj * 16] = f2bf(acc[mi][nj][r] + bb[nj]);
    }
  }
}

// ---------- per-token 32x32 head attention ----------
__global__ __launch_bounds__(256) void attn_kernel(const unsigned short* __restrict__ qkv,
                                                   float* __restrict__ out) {
  __shared__ float sQ[32 * 132];
  __shared__ float sK[32 * 132];
  __shared__ float sV[32 * 132];
  __shared__ float sP[32 * 33];

  int m = blockIdx.x;
  int tid = threadIdx.x;
  const unsigned short* gq = qkv + (size_t)m * HIDDEN;
  const unsigned short* gk = gq + (size_t)M_TOK * HIDDEN;
  const unsigned short* gv = gk + (size_t)M_TOK * HIDDEN;

  int row = tid >> 3;
  int cb = (tid & 7) << 4;
  int go = row * 128 + cb;
  int lo = row * 132 + cb;
  {
    u16x8 x0 = *(const u16x8*)(gq + go);
    u16x8 x1 = *(const u16x8*)(gq + go + 8);
#pragma unroll
    for (int j = 0; j < 8; ++j) { sQ[lo + j] = bf2f(x0[j]); sQ[lo + 8 + j] = bf2f(x1[j]); }
    x0 = *(const u16x8*)(gk + go);
    x1 = *(const u16x8*)(gk + go + 8);
#pragma unroll
    for (int j = 0; j < 8; ++j) { sK[lo + j] = bf2f(x0[j]); sK[lo + 8 + j] = bf2f(x1[j]); }
    x0 = *(const u16x8*)(gv + go);
    x1 = *(const u16x8*)(gv + go + 8);
#pragma unroll
    for (int j = 0; j < 8; ++j) { sV[lo + j] = bf2f(x0[j]); sV[lo + 8 + j] = bf2f(x1[j]); }
  }
  __syncthreads();

  int h = tid >> 3;
  int t4 = (tid & 7) << 2;
  const f32x4* qr = (const f32x4*)(sQ + h * 132);
  const f32x4* k0 = (const f32x4*)(sK + (t4 + 0) * 132);
  const f32x4* k1 = (const f32x4*)(sK + (t4 + 1) * 132);
  const f32x4* k2 = (const f32x4*)(sK + (t4 + 2) * 132);
  const f32x4* k3 = (const f32x4*)(sK + (t4 + 3) * 132);
  float s0 = 0.f, s1 = 0.f, s2 = 0.f, s3 = 0.f;
#pragma unroll
  for (int d = 0; d < 32; ++d) {
    f32x4 q = qr[d];
    f32x4 a = k0[d]; s0 += q.x * a.x + q.y * a.y + q.z * a.z + q.w * a.w;
    f32x4 b = k1[d]; s1 += q.x * b.x + q.y * b.y + q.z * b.z + q.w * b.w;
    f32x4 c = k2[d]; s2 += q.x * c.x + q.y * c.y + q.z * c.z + q.w * c.w;
    f32x4 e = k3[d]; s3 += q.x * e.x + q.y * e.y + q.z * e.z + q.w * e.w;
  }
  const float scale = 0.08838834764831845f;  // 1/sqrt(128)
  s0 *= scale; s1 *= scale; s2 *= scale; s3 *= scale;
  float mx = fmaxf(fmaxf(s0, s1), fmaxf(s2, s3));
  mx = fmaxf(mx, __shfl_xor(mx, 1));
  mx = fmaxf(mx, __shfl_xor(mx, 2));
  mx = fmaxf(mx, __shfl_xor(mx, 4));
  float e0 = __expf(s0 - mx), e1 = __expf(s1 - mx), e2 = __expf(s2 - mx), e3 = __expf(s3 - mx);
  float sum = e0 + e1 + e2 + e3;
  sum += __shfl_xor(sum, 1);
  sum += __shfl_xor(sum, 2);
  sum += __shfl_xor(sum, 4);
  float inv = 1.0f / sum;
  sP[h * 33 + t4 + 0] = e0 * inv;
  sP[h * 33 + t4 + 1] = e1 * inv;
  sP[h * 33 + t4 + 2] = e2 * inv;
  sP[h * 33 + t4 + 3] = e3 * inv;
  __syncthreads();

  int d0 = (tid & 7) << 4;
  f32x4 o0 = {0.f, 0.f, 0.f, 0.f}, o1 = o0, o2 = o0, o3 = o0;
  const float* pr = sP + h * 33;
#pragma unroll
  for (int t = 0; t < 32; ++t) {
    float p = pr[t];
    const f32x4* vr = (const f32x4*)(sV + t * 132 + d0);
    o0 += p * vr[0];
    o1 += p * vr[1];
    o2 += p * vr[2];
    o3 += p * vr[3];
  }
  f32x4* op = (f32x4*)(out + (size_t)m * HIDDEN + h * 128 + d0);
  op[0] = o0; op[1] = o1; op[2] = o2; op[3] = o3;
}

extern "C" void kernel_launch(void* const* d_in, const int* in_sizes, int n_in,
                              void* d_out, int out_size, void* d_ws, size_t ws_size,
                              hipStream_t stream) {
  const float* hs = (const float*)d_in[0];
  const float* wq = (const float*)d_in[1];
  const float* bq = (const float*)d_in[2];
  const float* wk = (const float*)d_in[3];
  const float* bk = (const float*)d_in[4];
  const float* wv = (const float*)d_in[5];
  const float* bv = (const float*)d_in[6];
  // wl/bl latent projection: unused by output — skipped.

  char* ws = (char*)d_ws;
  const size_t HS_OFF = 0;                    // 64 MiB
  const size_t W_OFF = 67108864;              // 96 MiB
  const size_t QKV_OFF = 167772160;           // 192 MiB
  const size_t BIAS_OFF = 369098752;          // 48 KiB
  const size_t NEED = 369147904;
  if (ws_size < NEED) return;

  unsigned short* hsb = (unsigned short*)(ws + HS_OFF);
  unsigned short* wb = (unsigned short*)(ws + W_OFF);
  unsigned short* qkv = (unsigned short*)(ws + QKV_OFF);
  float* bias = (float*)(ws + BIAS_OFF);

  cvt_kernel<<<16384, 256, 0, stream>>>(hs, hsb, 4194304);
  cvt_kernel<<<8192, 256, 0, stream>>>(wq, wb, 2097152);
  cvt_kernel<<<8192, 256, 0, stream>>>(wk, wb + 16777216, 2097152);
  cvt_kernel<<<8192, 256, 0, stream>>>(wv, wb + 33554432, 2097152);
  hipMemcpyAsync(bias, bq, 16384, hipMemcpyDeviceToDevice, stream);
  hipMemcpyAsync(bias + 4096, bk, 16384, hipMemcpyDeviceToDevice, stream);
  hipMemcpyAsync(bias + 8192, bv, 16384, hipMemcpyDeviceToDevice, stream);

  gemm_qkv<<<1536, 512, 0, stream>>>(hsb, wb, bias, qkv);   // 8 XCD x 4 tm x 48 tn
  attn_kernel<<<8192, 256, 0, stream>>>(qkv, (float*)d_out);
}